// Round 6
// baseline (39.024 us; speedup 1.0000x reference)
//
#include <hip/hip_runtime.h>
#include <hip/hip_bf16.h>

// Problem constants (B=4, T=4096, C=2048, E=64)
#define N_TOK   16384
#define C_DIM   2048
#define E_DIM   64
#define P_OFF   (N_TOK * E_DIM)        // 1048576 — end of probs section
#define FB_OFF  P_OFF                  // fallback_count scalar
#define LG_OFF  (P_OFF + 1)            // logits section
#define AM_OFF  (2 * P_OFF + 1)        // activation_mask section

typedef __attribute__((ext_vector_type(8))) short bf16x8;  // 8 bf16 in 4 VGPRs
typedef __attribute__((ext_vector_type(4))) float f32x4;

static __device__ __forceinline__ unsigned short f2bf_rtn(float f) {
    unsigned u = __float_as_uint(f);
    unsigned r = u + 0x7FFFu + ((u >> 16) & 1u);   // round-to-nearest-even
    return (unsigned short)(r >> 16);
}

// ---------------------------------------------------------------------------
// Kernel 1: prepack sim_matrix [2048,64] f32 -> bf16 (RTN) MFMA fragments.
// kk-step it (32 k): layout [it(64)][nb(4)][lane(64)][i(8)] shorts (256 KB).
// Content: lane l, elem i -> sim[it*32 + (l>>4)*8 + i][nb*16 + (l&15)]
// Also zero-initializes the fallback counter in d_out.
// ---------------------------------------------------------------------------
__global__ void gating_prepack(const float* __restrict__ sim,
                               unsigned short* __restrict__ Bpk,
                               float* __restrict__ out) {
    int tid = blockIdx.x * 256 + threadIdx.x;
    if (tid == 0) out[FB_OFF] = 0.0f;
    if (tid >= C_DIM * E_DIM) return;
    int k = tid >> 6;
    int e = tid & 63;
    float v = sim[tid];                       // sim[k*64 + e]
    int it = k >> 5;                          // kk-step 0..63
    int gr = (k >> 3) & 3;
    int i  = k & 7;
    int lane = gr * 16 + (e & 15);
    int nb   = e >> 4;
    Bpk[it * 2048 + nb * 512 + lane * 8 + i] = f2bf_rtn(v);
}

// ---------------------------------------------------------------------------
// Kernel 2: fused affinity-GEMM (bf16 MFMA) + gating epilogue.
// Grid 1024 x 256 (4 waves). Block owns 16 tokens; wave w computes K-quarter
// w*512.. as 8 chunks of 2 kk-steps. Per chunk, program order is strictly
// {burst A(c+1); burst B(c+1); compute chunk c}. Because vmcnt drains in
// ISSUE order, this guarantees: wait(A(c)) drains only A(c); wait(B(c))
// drains only B(c); chunk c+1's loads always stay in flight. (All rolling
// ring designs coupled A's effective distance to B's wait cadence.)
// Cross-wave reduction via LDS; wave w finishes C/D reg r = w.
// ---------------------------------------------------------------------------
__global__ __launch_bounds__(256, 4)
void gating_main(const float* __restrict__ x,
                 const unsigned short* __restrict__ Bpk,
                 const float* __restrict__ gates,
                 float* __restrict__ out) {
    __shared__ float red[4][16][64];   // [wave][nb*4+r][lane] = 16 KB

    const int tid = threadIdx.x;
    const int l   = tid & 63;
    const int w   = tid >> 6;          // wave id == K-split index == C/D reg r
    const int row0 = blockIdx.x * 16;
    const int g    = l >> 4;           // k-slot group / token subgroup
    const int e0   = l & 15;
    // A: lane's token row, wave's K-quarter; kk-step it reads xr+it*32 (2xfloat4)
    const float* xr = x + (size_t)(row0 + e0) * C_DIM + w * 512 + g * 8;
    // B: per kk-step stride 2048 shorts; lane's fragment base
    const unsigned short* bw = Bpk + (size_t)w * 16 * 2048 + l * 8;

    f32x4 acc[4];
#pragma unroll
    for (int nb = 0; nb < 4; ++nb) acc[nb] = (f32x4)0.0f;

    float4 Ac[2][2][2];   // [buf][step][half] : 32 VGPR
    bf16x8 Bc[2][2][4];   // [buf][step][nb]   : 64 VGPR

    // ---- prologue: chunk 0 bursts (A first, then B) ----
#pragma unroll
    for (int st = 0; st < 2; ++st) {
        const float* ap = xr + st * 32;
        Ac[0][st][0] = *(const float4*)ap;
        Ac[0][st][1] = *(const float4*)(ap + 4);
    }
#pragma unroll
    for (int st = 0; st < 2; ++st)
#pragma unroll
        for (int f = 0; f < 4; ++f)
            Bc[0][st][f] = *(const bf16x8*)(bw + st * 2048 + f * 512);

    // ---- 8 chunks of 2 kk-steps, fully unrolled ----
#pragma unroll
    for (int c = 0; c < 8; ++c) {
        const int cur = c & 1, nxt = cur ^ 1;

        if (c < 7) {
            // burst A for chunk c+1 — issued FIRST
#pragma unroll
            for (int st = 0; st < 2; ++st) {
                const float* ap = xr + ((c + 1) * 2 + st) * 32;
                Ac[nxt][st][0] = *(const float4*)ap;
                Ac[nxt][st][1] = *(const float4*)(ap + 4);
            }
            // burst B for chunk c+1 — issued SECOND
#pragma unroll
            for (int st = 0; st < 2; ++st)
#pragma unroll
                for (int f = 0; f < 4; ++f)
                    Bc[nxt][st][f] = *(const bf16x8*)(bw + ((c + 1) * 2 + st) * 2048 + f * 512);
        }

        // compute chunk c
#pragma unroll
        for (int st = 0; st < 2; ++st) {
            float av[8] = {Ac[cur][st][0].x, Ac[cur][st][0].y,
                           Ac[cur][st][0].z, Ac[cur][st][0].w,
                           Ac[cur][st][1].x, Ac[cur][st][1].y,
                           Ac[cur][st][1].z, Ac[cur][st][1].w};
            bf16x8 ah;
#pragma unroll
            for (int i = 0; i < 8; ++i) ah[i] = (short)f2bf_rtn(av[i]);
#pragma unroll
            for (int nb = 0; nb < 4; ++nb)
                acc[nb] = __builtin_amdgcn_mfma_f32_16x16x32_bf16(ah, Bc[cur][st][nb], acc[nb], 0, 0, 0);
        }
    }

    // ---- cross-wave K reduction via LDS (conflict-free layout) ----
#pragma unroll
    for (int nb = 0; nb < 4; ++nb)
#pragma unroll
        for (int r = 0; r < 4; ++r)
            red[w][nb * 4 + r][l] = acc[nb][r];
    __syncthreads();

    float tot[4];
#pragma unroll
    for (int nb = 0; nb < 4; ++nb)
        tot[nb] = red[0][nb * 4 + w][l] + red[1][nb * 4 + w][l]
                + red[2][nb * 4 + w][l] + red[3][nb * 4 + w][l];

    // ---- epilogue: wave w handles tokens t = row0 + g*4 + w ----
    float sig[4];
#pragma unroll
    for (int nb = 0; nb < 4; ++nb)
        sig[nb] = 1.0f / (1.0f + expf(-gates[nb * 16 + e0]));

    const int t = row0 + g * 4 + w;
    float lg[4];
    bool  act[4];
    int   lcnt = 0;
    float lmax = -3.4e38f;
#pragma unroll
    for (int nb = 0; nb < 4; ++nb) {
        lg[nb]  = tot[nb] - sig[nb];
        act[nb] = lg[nb] > 0.0f;
        if (act[nb]) { lcnt++; lmax = fmaxf(lmax, lg[nb]); }
    }
    int cnt = lcnt;
    float mx = lmax;
#pragma unroll
    for (int m = 1; m < 16; m <<= 1) {
        cnt += __shfl_xor(cnt, m, 16);
        mx   = fmaxf(mx, __shfl_xor(mx, m, 16));
    }

    float p[4], am[4];
    if (cnt > 0) {
        float ex[4], ls = 0.0f;
#pragma unroll
        for (int nb = 0; nb < 4; ++nb) {
            ex[nb] = act[nb] ? expf(lg[nb] - mx) : 0.0f;
            ls += ex[nb];
        }
        float Z = ls;
#pragma unroll
        for (int m = 1; m < 16; m <<= 1) Z += __shfl_xor(Z, m, 16);
        float rz = 1.0f / Z;
#pragma unroll
        for (int nb = 0; nb < 4; ++nb) {
            p[nb]  = ex[nb] * rz;
            am[nb] = act[nb] ? 1.0f : 0.0f;
        }
    } else {
        // fallback: top-32 of the 64 logits (ties -> lower expert index).
        // All logits <= 0 here, so probs are uniform 1/32 over the set.
        unsigned selm = 0;
        for (int it = 0; it < 32; ++it) {
            float bv = -3.4e38f;
            int   bi = 127;
#pragma unroll
            for (int nb = 0; nb < 4; ++nb) {
                if (!((selm >> nb) & 1)) {
                    float v = lg[nb];
                    int   e = nb * 16 + e0;
                    if (v > bv || (v == bv && e < bi)) { bv = v; bi = e; }
                }
            }
#pragma unroll
            for (int m = 1; m < 16; m <<= 1) {
                float ov = __shfl_xor(bv, m, 16);
                int   oi = __shfl_xor(bi, m, 16);
                if (ov > bv || (ov == bv && oi < bi)) { bv = ov; bi = oi; }
            }
            if ((bi & 15) == e0) selm |= 1u << (bi >> 4);
        }
#pragma unroll
        for (int nb = 0; nb < 4; ++nb) {
            bool s_ = (selm >> nb) & 1;
            p[nb]  = s_ ? (1.0f / 32.0f) : 0.0f;
            am[nb] = s_ ? 1.0f : 0.0f;
        }
        if (e0 == 0) atomicAdd(&out[FB_OFF], 1.0f);
    }

#pragma unroll
    for (int nb = 0; nb < 4; ++nb) {
        int idx = t * 64 + nb * 16 + e0;
        out[idx]          = p[nb];
        out[LG_OFF + idx] = lg[nb];
        out[AM_OFF + idx] = am[nb];
    }
}

// ---------------------------------------------------------------------------
extern "C" void kernel_launch(void* const* d_in, const int* in_sizes, int n_in,
                              void* d_out, int out_size, void* d_ws, size_t ws_size,
                              hipStream_t stream) {
    const float* x     = (const float*)d_in[0];   // [4,4096,2048] f32
    const float* sim   = (const float*)d_in[1];   // [2048,64] f32
    const float* gates = (const float*)d_in[2];   // [64] f32
    float* out = (float*)d_out;
    unsigned short* Bpk = (unsigned short*)d_ws;  // 256 KB prepacked B (bf16)

    gating_prepack<<<512, 256, 0, stream>>>(sim, Bpk, out);
    gating_main<<<1024, 256, 0, stream>>>(x, Bpk, gates, out);
}